// Round 8
// baseline (39.014 us; speedup 1.0000x reference)
//
#include <hip/hip_runtime.h>

#define KDIM 1024
#define DDIM 128
#define LDP  132   // LDS row stride (floats): row addr mod 32 banks = row*4 -> <=2-way (free)
#define TM   32    // tile rows per block
#define TN   64    // tile cols per block
#define NPROBE 8   // graph-node overhead probes

typedef float f2 __attribute__((ext_vector_type(2)));

// ---------------------------------------------------------------------------
// Kernel 1: U = span @ (W1a + W1c) + b1 ; V = ant @ (W1b - W1c)
// 256 blocks x 256 threads; 8 rows of one matrix per block. (identical to R6)
// ---------------------------------------------------------------------------
__global__ __launch_bounds__(256) void prep_uv(
    const float* __restrict__ span, const float* __restrict__ ant,
    const float* __restrict__ W1,   const float* __restrict__ b1,
    float* __restrict__ U, float* __restrict__ V)
{
    __shared__ float a_lds[8 * DDIM];    // 4 KB

    const int tid  = threadIdx.x;
    const int mat  = blockIdx.x & 1;     // 0 -> U (span), 1 -> V (ant)
    const int rblk = blockIdx.x >> 1;    // 0..127, 8 rows each
    const float* __restrict__ A = mat ? ant : span;
    float* __restrict__ outp    = mat ? V : U;

    ((float4*)a_lds)[tid] = ((const float4*)(A + rblk * 8 * DDIM))[tid];
    __syncthreads();

    const int c  = tid & 127;
    const int rg = tid >> 7;             // 0/1 -> rows rg*4..rg*4+3
    const float binit = mat ? 0.0f : b1[c];
    float acc0 = binit, acc1 = binit, acc2 = binit, acc3 = binit;

    const float* __restrict__ Wx = W1 + (mat ? DDIM * DDIM : 0);
    const float* __restrict__ Wc = W1 + 2 * DDIM * DDIM;
    const float sgn = mat ? -1.0f : 1.0f;

#pragma unroll 4
    for (int d0 = 0; d0 < DDIM; d0 += 4) {
        float w0 = Wx[(d0 + 0) * DDIM + c] + sgn * Wc[(d0 + 0) * DDIM + c];
        float w1 = Wx[(d0 + 1) * DDIM + c] + sgn * Wc[(d0 + 1) * DDIM + c];
        float w2 = Wx[(d0 + 2) * DDIM + c] + sgn * Wc[(d0 + 2) * DDIM + c];
        float w3 = Wx[(d0 + 3) * DDIM + c] + sgn * Wc[(d0 + 3) * DDIM + c];
        float4 a0 = *(const float4*)&a_lds[(rg * 4 + 0) * DDIM + d0];
        float4 a1 = *(const float4*)&a_lds[(rg * 4 + 1) * DDIM + d0];
        float4 a2 = *(const float4*)&a_lds[(rg * 4 + 2) * DDIM + d0];
        float4 a3 = *(const float4*)&a_lds[(rg * 4 + 3) * DDIM + d0];
        acc0 += a0.x * w0 + a0.y * w1 + a0.z * w2 + a0.w * w3;
        acc1 += a1.x * w0 + a1.y * w1 + a1.z * w2 + a1.w * w3;
        acc2 += a2.x * w0 + a2.y * w1 + a2.z * w2 + a2.w * w3;
        acc3 += a3.x * w0 + a3.y * w1 + a3.z * w2 + a3.w * w3;
    }
    const int rbase = rblk * 8 + rg * 4;
    outp[(rbase + 0) * DDIM + c] = acc0;
    outp[(rbase + 1) * DDIM + c] = acc1;
    outp[(rbase + 2) * DDIM + c] = acc2;
    outp[(rbase + 3) * DDIM + c] = acc3;
}

// ---------------------------------------------------------------------------
// Kernel 2: identical to round 6.
// ---------------------------------------------------------------------------
__global__ __launch_bounds__(256) void pair_score(
    const float* __restrict__ U, const float* __restrict__ V,
    const float* __restrict__ W2, const float* __restrict__ b2,
    float* __restrict__ out)
{
    const int bj  = blockIdx.x;   // 0..15, 64-col strip
    const int bi  = blockIdx.y;   // 0..31, 32-row strip
    const int tid = threadIdx.x;

    if (bi < 2 * bj) {
        const float4 z4 = make_float4(0.f, 0.f, 0.f, 0.f);
#pragma unroll
        for (int k = 0; k < 2; ++k) {
            int idx = tid + k * 256;          // 0..511
            int r   = idx >> 4;               // 16 float4 per 64-col row
            int c4  = idx & 15;
            *(float4*)&out[(bi * TM + r) * KDIM + bj * TN + c4 * 4] = z4;
        }
        return;
    }

    __shared__ float Ul[TM * LDP];            // 16.9 KB
    __shared__ float Vl[TN * LDP];            // 33.8 KB
    __shared__ float W2l[DDIM];

    {
        const float4* us = (const float4*)(U + bi * TM * DDIM);
        const float4* vs = (const float4*)(V + bj * TN * DDIM);
#pragma unroll
        for (int k = 0; k < 4; ++k) {
            int idx = tid + k * 256;          // 0..1023
            *(float4*)&Ul[(idx >> 5) * LDP + (idx & 31) * 4] = us[idx];
        }
#pragma unroll
        for (int k = 0; k < 8; ++k) {
            int idx = tid + k * 256;          // 0..2047
            *(float4*)&Vl[(idx >> 5) * LDP + (idx & 31) * 4] = vs[idx];
        }
        if (tid < 32) *(float4*)&W2l[tid * 4] = *(const float4*)&W2[tid * 4];
    }
    __syncthreads();

    const int ti = tid >> 4;                  // 0..15, i = ti + 16a (a<2)
    const int tj = tid & 15;                  // 0..15, j = tj + 16b (b<4)
    const f2 z2 = {0.f, 0.f};

    f2 acc[2][4][2];
#pragma unroll
    for (int a = 0; a < 2; ++a)
#pragma unroll
        for (int b = 0; b < 4; ++b) { acc[a][b][0] = z2; acc[a][b][1] = z2; }

#pragma unroll 4
    for (int d = 0; d < DDIM; d += 4) {
        f2 ul[2][2], vl[4][2], w[2];
        {
            float4 x = *(const float4*)&W2l[d];
            w[0] = f2{x.x, x.y}; w[1] = f2{x.z, x.w};
        }
#pragma unroll
        for (int a = 0; a < 2; ++a) {
            float4 x = *(const float4*)&Ul[(ti + 16 * a) * LDP + d];
            ul[a][0] = f2{x.x, x.y}; ul[a][1] = f2{x.z, x.w};
        }
#pragma unroll
        for (int b = 0; b < 4; ++b) {
            float4 x = *(const float4*)&Vl[(tj + 16 * b) * LDP + d];
            vl[b][0] = f2{x.x, x.y}; vl[b][1] = f2{x.z, x.w};
        }
#pragma unroll
        for (int a = 0; a < 2; ++a)
#pragma unroll
            for (int b = 0; b < 4; ++b) {
                f2 t0 = __builtin_elementwise_max(ul[a][0] + vl[b][0], z2);
                f2 t1 = __builtin_elementwise_max(ul[a][1] + vl[b][1], z2);
                acc[a][b][0] += t0 * w[0];
                acc[a][b][1] += t1 * w[1];
            }
    }

    const float b2v = b2[0];
#pragma unroll
    for (int a = 0; a < 2; ++a) {
        const int gi = bi * TM + ti + 16 * a;
#pragma unroll
        for (int b = 0; b < 4; ++b) {
            const int gj = bj * TN + tj + 16 * b;
            f2 s2 = acc[a][b][0] + acc[a][b][1];
            float s = s2.x + s2.y + b2v;
            out[gi * KDIM + gj] = (gi > gj) ? s : 0.f;
        }
    }
}

// ---------------------------------------------------------------------------
// Probe kernel: measures per-graph-node overhead. 1 block, 64 threads,
// writes one float to an unused d_ws slot (beyond the 1 MB U/V region).
// Deterministic, never touches d_out.
// ---------------------------------------------------------------------------
__global__ __launch_bounds__(64) void nop_probe(float* __restrict__ p, int tag)
{
    if (threadIdx.x == 0) p[tag] = (float)(tag + 1);
}

// ---------------------------------------------------------------------------
extern "C" void kernel_launch(void* const* d_in, const int* in_sizes, int n_in,
                              void* d_out, int out_size, void* d_ws, size_t ws_size,
                              hipStream_t stream)
{
    const float* span = (const float*)d_in[0];
    const float* ant  = (const float*)d_in[1];
    const float* W1   = (const float*)d_in[2];
    const float* b1   = (const float*)d_in[3];
    const float* W2   = (const float*)d_in[4];
    const float* b2   = (const float*)d_in[5];
    float* out = (float*)d_out;

    float* U = (float*)d_ws;                 // 1024*128 floats (512 KB)
    float* V = U + KDIM * DDIM;              // next 512 KB
    float* probe = V + KDIM * DDIM;          // dummy slots at +1 MB

    prep_uv<<<dim3(256), 256, 0, stream>>>(span, ant, W1, b1, U, V);
    pair_score<<<dim3(16, 32), 256, 0, stream>>>(U, V, W2, b2, out);

    // NPROBE probe nodes: dur_us = baseline(26.5) + NPROBE * n_node
    for (int t = 0; t < NPROBE; ++t)
        nop_probe<<<dim3(1), 64, 0, stream>>>(probe, t);
}

// Round 10
// 33.735 us; speedup vs baseline: 1.1565x; 1.1565x over previous
//
#include <hip/hip_runtime.h>

#define KDIM 1024
#define DDIM 128
#define LDP  132   // LDS row stride (floats): row banks = 4*row mod 32 -> <=2-way (free)
#define TM   32    // tile rows per block
#define TN   64    // tile cols per block

typedef float f2 __attribute__((ext_vector_type(2)));

// ---------------------------------------------------------------------------
// Kernel 1: U = span @ (W1a + W1c) + b1 ; V = ant @ (W1b - W1c)
// 256 blocks x 256 threads; 8 rows of one matrix per block. (R6-proven)
// ---------------------------------------------------------------------------
__global__ __launch_bounds__(256) void prep_uv(
    const float* __restrict__ span, const float* __restrict__ ant,
    const float* __restrict__ W1,   const float* __restrict__ b1,
    float* __restrict__ U, float* __restrict__ V)
{
    __shared__ float a_lds[8 * DDIM];    // 4 KB

    const int tid  = threadIdx.x;
    const int mat  = blockIdx.x & 1;     // 0 -> U (span), 1 -> V (ant)
    const int rblk = blockIdx.x >> 1;    // 0..127, 8 rows each
    const float* __restrict__ A = mat ? ant : span;
    float* __restrict__ outp    = mat ? V : U;

    ((float4*)a_lds)[tid] = ((const float4*)(A + rblk * 8 * DDIM))[tid];
    __syncthreads();

    const int c  = tid & 127;
    const int rg = tid >> 7;             // 0/1 -> rows rg*4..rg*4+3
    const float binit = mat ? 0.0f : b1[c];
    float acc0 = binit, acc1 = binit, acc2 = binit, acc3 = binit;

    const float* __restrict__ Wx = W1 + (mat ? DDIM * DDIM : 0);
    const float* __restrict__ Wc = W1 + 2 * DDIM * DDIM;
    const float sgn = mat ? -1.0f : 1.0f;

#pragma unroll 4
    for (int d0 = 0; d0 < DDIM; d0 += 4) {
        float w0 = Wx[(d0 + 0) * DDIM + c] + sgn * Wc[(d0 + 0) * DDIM + c];
        float w1 = Wx[(d0 + 1) * DDIM + c] + sgn * Wc[(d0 + 1) * DDIM + c];
        float w2 = Wx[(d0 + 2) * DDIM + c] + sgn * Wc[(d0 + 2) * DDIM + c];
        float w3 = Wx[(d0 + 3) * DDIM + c] + sgn * Wc[(d0 + 3) * DDIM + c];
        float4 a0 = *(const float4*)&a_lds[(rg * 4 + 0) * DDIM + d0];
        float4 a1 = *(const float4*)&a_lds[(rg * 4 + 1) * DDIM + d0];
        float4 a2 = *(const float4*)&a_lds[(rg * 4 + 2) * DDIM + d0];
        float4 a3 = *(const float4*)&a_lds[(rg * 4 + 3) * DDIM + d0];
        acc0 += a0.x * w0 + a0.y * w1 + a0.z * w2 + a0.w * w3;
        acc1 += a1.x * w0 + a1.y * w1 + a1.z * w2 + a1.w * w3;
        acc2 += a2.x * w0 + a2.y * w1 + a2.z * w2 + a2.w * w3;
        acc3 += a3.x * w0 + a3.y * w1 + a3.z * w2 + a3.w * w3;
    }
    const int rbase = rblk * 8 + rg * 4;
    outp[(rbase + 0) * DDIM + c] = acc0;
    outp[(rbase + 1) * DDIM + c] = acc1;
    outp[(rbase + 2) * DDIM + c] = acc2;
    outp[(rbase + 3) * DDIM + c] = acc3;
}

// ---------------------------------------------------------------------------
// Kernel 2: out[i][j] = (i>j) ? b2 + sum_c relu(U[i][c]+V[j][c])*W2[c] : 0
// grid (16,32): 32x64 tiles, 128 threads, 4x4 micro-tile.
//   i = ti + 8a (ti=tid>>4, a<4), j = tj + 16b (tj=tid&15, b<4)
// U reads: 4 addrs/wave, 16-lane broadcast, conflict-free.
// V reads: 2-way bank alias (free). W2: uniform scalar loads (no LDS).
// LDS 50.7 KB -> 3 blocks/CU. Compute iff bi >= 2*bj (272 blocks, full chip).
// ---------------------------------------------------------------------------
__global__ __launch_bounds__(128) void pair_score(
    const float* __restrict__ U, const float* __restrict__ V,
    const float* __restrict__ W2, const float* __restrict__ b2,
    float* __restrict__ out)
{
    const int bj  = blockIdx.x;   // 0..15, 64-col strip
    const int bi  = blockIdx.y;   // 0..31, 32-row strip
    const int tid = threadIdx.x;

    if (bi < 2 * bj) {
        // strictly-upper tile: zero-fill this 32x64 tile. 512 float4, 4/thread.
        const float4 z4 = make_float4(0.f, 0.f, 0.f, 0.f);
#pragma unroll
        for (int k = 0; k < 4; ++k) {
            int idx = tid + k * 128;          // 0..511
            int r   = idx >> 4;               // 16 float4 per 64-col row
            int c4  = idx & 15;
            *(float4*)&out[(bi * TM + r) * KDIM + bj * TN + c4 * 4] = z4;
        }
        return;
    }

    __shared__ float Ul[TM * LDP];            // 16.9 KB
    __shared__ float Vl[TN * LDP];            // 33.8 KB

    {   // stage: U tile 1024 float4 (8/thread), V tile 2048 float4 (16/thread)
        const float4* us = (const float4*)(U + bi * TM * DDIM);
        const float4* vs = (const float4*)(V + bj * TN * DDIM);
#pragma unroll
        for (int k = 0; k < 8; ++k) {
            int idx = tid + k * 128;          // 0..1023
            *(float4*)&Ul[(idx >> 5) * LDP + (idx & 31) * 4] = us[idx];
        }
#pragma unroll
        for (int k = 0; k < 16; ++k) {
            int idx = tid + k * 128;          // 0..2047
            *(float4*)&Vl[(idx >> 5) * LDP + (idx & 31) * 4] = vs[idx];
        }
    }
    __syncthreads();

    const int ti = tid >> 4;                  // 0..7,  i = ti + 8a  (a<4)
    const int tj = tid & 15;                  // 0..15, j = tj + 16b (b<4)
    const f2 z2 = {0.f, 0.f};

    f2 acc[4][4][2];
#pragma unroll
    for (int a = 0; a < 4; ++a)
#pragma unroll
        for (int b = 0; b < 4; ++b) { acc[a][b][0] = z2; acc[a][b][1] = z2; }

#pragma unroll 4
    for (int d = 0; d < DDIM; d += 4) {
        // W2 slice: uniform address (compile-time d in unrolled loop) -> s_load
        const f2 w0 = *(const f2*)&W2[d];
        const f2 w1 = *(const f2*)&W2[d + 2];

        f2 ul[4][2], vl[4][2];
#pragma unroll
        for (int a = 0; a < 4; ++a) {
            float4 x = *(const float4*)&Ul[(ti + 8 * a) * LDP + d];
            ul[a][0] = f2{x.x, x.y}; ul[a][1] = f2{x.z, x.w};
        }
#pragma unroll
        for (int b = 0; b < 4; ++b) {
            float4 x = *(const float4*)&Vl[(tj + 16 * b) * LDP + d];
            vl[b][0] = f2{x.x, x.y}; vl[b][1] = f2{x.z, x.w};
        }
#pragma unroll
        for (int a = 0; a < 4; ++a)
#pragma unroll
            for (int b = 0; b < 4; ++b) {
                f2 t0 = __builtin_elementwise_max(ul[a][0] + vl[b][0], z2);
                f2 t1 = __builtin_elementwise_max(ul[a][1] + vl[b][1], z2);
                acc[a][b][0] += t0 * w0;
                acc[a][b][1] += t1 * w1;
            }
    }

    const float b2v = b2[0];
#pragma unroll
    for (int a = 0; a < 4; ++a) {
        const int gi = bi * TM + ti + 8 * a;
#pragma unroll
        for (int b = 0; b < 4; ++b) {
            const int gj = bj * TN + tj + 16 * b;
            f2 s2 = acc[a][b][0] + acc[a][b][1];
            float s = s2.x + s2.y + b2v;
            out[gi * KDIM + gj] = (gi > gj) ? s : 0.f;
        }
    }
}

// ---------------------------------------------------------------------------
extern "C" void kernel_launch(void* const* d_in, const int* in_sizes, int n_in,
                              void* d_out, int out_size, void* d_ws, size_t ws_size,
                              hipStream_t stream)
{
    const float* span = (const float*)d_in[0];
    const float* ant  = (const float*)d_in[1];
    const float* W1   = (const float*)d_in[2];
    const float* b1   = (const float*)d_in[3];
    const float* W2   = (const float*)d_in[4];
    const float* b2   = (const float*)d_in[5];
    float* out = (float*)d_out;

    float* U = (float*)d_ws;                 // 1024*128 floats (512 KB)
    float* V = U + KDIM * DDIM;              // next 512 KB (1 MB ws total)

    prep_uv<<<dim3(256), 256, 0, stream>>>(span, ant, W1, b1, U, V);
    pair_score<<<dim3(16, 32), 128, 0, stream>>>(U, V, W2, b2, out);
}

// Round 11
// 27.135 us; speedup vs baseline: 1.4378x; 1.2433x over previous
//
#include <hip/hip_runtime.h>

#define KDIM 1024
#define DDIM 128
#define LDP  132   // LDS row stride (floats): row start bank = 4*row mod 32 -> conflict-free by design
#define TS   32    // 32x32 output tiles

typedef float f2 __attribute__((ext_vector_type(2)));

// ---------------------------------------------------------------------------
// Kernel 1: U = span @ (W1a + W1c) + b1 ; V = ant @ (W1b - W1c)
// 256 blocks x 256 threads; 8 rows of one matrix per block. (R6-proven)
// ---------------------------------------------------------------------------
__global__ __launch_bounds__(256) void prep_uv(
    const float* __restrict__ span, const float* __restrict__ ant,
    const float* __restrict__ W1,   const float* __restrict__ b1,
    float* __restrict__ U, float* __restrict__ V)
{
    __shared__ float a_lds[8 * DDIM];    // 4 KB

    const int tid  = threadIdx.x;
    const int mat  = blockIdx.x & 1;     // 0 -> U (span), 1 -> V (ant)
    const int rblk = blockIdx.x >> 1;    // 0..127, 8 rows each
    const float* __restrict__ A = mat ? ant : span;
    float* __restrict__ outp    = mat ? V : U;

    ((float4*)a_lds)[tid] = ((const float4*)(A + rblk * 8 * DDIM))[tid];
    __syncthreads();

    const int c  = tid & 127;
    const int rg = tid >> 7;             // 0/1 -> rows rg*4..rg*4+3
    const float binit = mat ? 0.0f : b1[c];
    float acc0 = binit, acc1 = binit, acc2 = binit, acc3 = binit;

    const float* __restrict__ Wx = W1 + (mat ? DDIM * DDIM : 0);
    const float* __restrict__ Wc = W1 + 2 * DDIM * DDIM;
    const float sgn = mat ? -1.0f : 1.0f;

#pragma unroll 4
    for (int d0 = 0; d0 < DDIM; d0 += 4) {
        float w0 = Wx[(d0 + 0) * DDIM + c] + sgn * Wc[(d0 + 0) * DDIM + c];
        float w1 = Wx[(d0 + 1) * DDIM + c] + sgn * Wc[(d0 + 1) * DDIM + c];
        float w2 = Wx[(d0 + 2) * DDIM + c] + sgn * Wc[(d0 + 2) * DDIM + c];
        float w3 = Wx[(d0 + 3) * DDIM + c] + sgn * Wc[(d0 + 3) * DDIM + c];
        float4 a0 = *(const float4*)&a_lds[(rg * 4 + 0) * DDIM + d0];
        float4 a1 = *(const float4*)&a_lds[(rg * 4 + 1) * DDIM + d0];
        float4 a2 = *(const float4*)&a_lds[(rg * 4 + 2) * DDIM + d0];
        float4 a3 = *(const float4*)&a_lds[(rg * 4 + 3) * DDIM + d0];
        acc0 += a0.x * w0 + a0.y * w1 + a0.z * w2 + a0.w * w3;
        acc1 += a1.x * w0 + a1.y * w1 + a1.z * w2 + a1.w * w3;
        acc2 += a2.x * w0 + a2.y * w1 + a2.z * w2 + a2.w * w3;
        acc3 += a3.x * w0 + a3.y * w1 + a3.z * w2 + a3.w * w3;
    }
    const int rbase = rblk * 8 + rg * 4;
    outp[(rbase + 0) * DDIM + c] = acc0;
    outp[(rbase + 1) * DDIM + c] = acc1;
    outp[(rbase + 2) * DDIM + c] = acc2;
    outp[(rbase + 3) * DDIM + c] = acc3;
}

// ---------------------------------------------------------------------------
// Kernel 2: out[i][j] = (i>j) ? b2 + sum_c relu(U[i][c]+V[j][c])*W2[c] : 0
// grid (32,32) of 32x32 tiles, 64 threads (1 wave), 4x4 micro-tile.
//   i = ti + 8a (ti=tid>>3), j = tj + 8b (tj=tid&7), a,b < 4
// U reads: banks 4*ti span all 32 -> conflict-free, 8-lane broadcast.
// V reads: banks 4*tj            -> conflict-free, 8-lane broadcast.
// W2 from LDS, same-address broadcast (free). No scalar loads in loop
// (R10 lesson: s_load shares lgkmcnt with ds_read -> full drains).
// LDS ~34 KB -> 4 blocks/CU. 528 compute blocks, 496 zero-fill blocks.
// ---------------------------------------------------------------------------
__global__ __launch_bounds__(64) void pair_score(
    const float* __restrict__ U, const float* __restrict__ V,
    const float* __restrict__ W2, const float* __restrict__ b2,
    float* __restrict__ out)
{
    const int bj  = blockIdx.x;   // column tile
    const int bi  = blockIdx.y;   // row tile
    const int tid = threadIdx.x;

    if (bi < bj) {
        // strictly-upper tile: zero-fill EXACTLY this 32x32 tile (256 float4).
        const float4 z4 = make_float4(0.f, 0.f, 0.f, 0.f);
#pragma unroll
        for (int k = 0; k < 4; ++k) {
            int idx = tid + k * 64;           // 0..255
            int r   = idx >> 3;               // 8 float4 per 32-col row
            int c4  = idx & 7;
            *(float4*)&out[(bi * TS + r) * KDIM + bj * TS + c4 * 4] = z4;
        }
        return;
    }

    __shared__ float Ul[TS * LDP];            // 16.9 KB
    __shared__ float Vl[TS * LDP];            // 16.9 KB
    __shared__ float W2l[DDIM];               // 0.5 KB

    {   // stage tiles: 1024 float4 each, 16 per thread
        const float4* us = (const float4*)(U + bi * TS * DDIM);
        const float4* vs = (const float4*)(V + bj * TS * DDIM);
#pragma unroll
        for (int k = 0; k < 16; ++k) {
            int idx = tid + k * 64;           // 0..1023
            int r   = idx >> 5;               // 32 float4 per row
            int c4  = idx & 31;
            *(float4*)&Ul[r * LDP + c4 * 4] = us[idx];
            *(float4*)&Vl[r * LDP + c4 * 4] = vs[idx];
        }
        if (tid < 32) *(float4*)&W2l[tid * 4] = *(const float4*)&W2[tid * 4];
    }
    __syncthreads();

    const int ti = tid >> 3;                  // 0..7, i = ti + 8a
    const int tj = tid & 7;                   // 0..7, j = tj + 8b
    const f2 z2 = {0.f, 0.f};

    f2 acc[4][4][2];
#pragma unroll
    for (int a = 0; a < 4; ++a)
#pragma unroll
        for (int b = 0; b < 4; ++b) { acc[a][b][0] = z2; acc[a][b][1] = z2; }

#pragma unroll 4
    for (int d = 0; d < DDIM; d += 4) {
        f2 ul[4][2], vl[4][2], w[2];
        {
            float4 x = *(const float4*)&W2l[d];
            w[0] = f2{x.x, x.y}; w[1] = f2{x.z, x.w};
        }
#pragma unroll
        for (int a = 0; a < 4; ++a) {
            float4 x = *(const float4*)&Ul[(ti + 8 * a) * LDP + d];
            ul[a][0] = f2{x.x, x.y}; ul[a][1] = f2{x.z, x.w};
        }
#pragma unroll
        for (int b = 0; b < 4; ++b) {
            float4 x = *(const float4*)&Vl[(tj + 8 * b) * LDP + d];
            vl[b][0] = f2{x.x, x.y}; vl[b][1] = f2{x.z, x.w};
        }
#pragma unroll
        for (int a = 0; a < 4; ++a)
#pragma unroll
            for (int b = 0; b < 4; ++b) {
                f2 t0 = __builtin_elementwise_max(ul[a][0] + vl[b][0], z2);
                f2 t1 = __builtin_elementwise_max(ul[a][1] + vl[b][1], z2);
                acc[a][b][0] += t0 * w[0];
                acc[a][b][1] += t1 * w[1];
            }
    }

    const float b2v = b2[0];
#pragma unroll
    for (int a = 0; a < 4; ++a) {
        const int gi = bi * TS + ti + 8 * a;
#pragma unroll
        for (int b = 0; b < 4; ++b) {
            const int gj = bj * TS + tj + 8 * b;
            f2 s2 = acc[a][b][0] + acc[a][b][1];
            float s = s2.x + s2.y + b2v;
            out[gi * KDIM + gj] = (gi > gj) ? s : 0.f;
        }
    }
}

// ---------------------------------------------------------------------------
extern "C" void kernel_launch(void* const* d_in, const int* in_sizes, int n_in,
                              void* d_out, int out_size, void* d_ws, size_t ws_size,
                              hipStream_t stream)
{
    const float* span = (const float*)d_in[0];
    const float* ant  = (const float*)d_in[1];
    const float* W1   = (const float*)d_in[2];
    const float* b1   = (const float*)d_in[3];
    const float* W2   = (const float*)d_in[4];
    const float* b2   = (const float*)d_in[5];
    float* out = (float*)d_out;

    float* U = (float*)d_ws;                 // 1024*128 floats (512 KB)
    float* V = U + KDIM * DDIM;              // next 512 KB (1 MB ws total)

    prep_uv<<<dim3(256), 256, 0, stream>>>(span, ant, W1, b1, U, V);
    pair_score<<<dim3(32, 32), 64, 0, stream>>>(U, V, W2, b2, out);
}

// Round 12
// 26.097 us; speedup vs baseline: 1.4950x; 1.0398x over previous
//
#include <hip/hip_runtime.h>

#define KDIM 1024
#define DDIM 128
#define LDP  132   // LDS row stride (floats): row start bank = 4*row mod 32
#define TS   32    // 32x32 output tiles

typedef float f2 __attribute__((ext_vector_type(2)));

// ---------------------------------------------------------------------------
// Kernel 1: U = span @ (W1a + W1c) + b1 ; V = ant @ (W1b - W1c)
// 256 blocks x 256 threads; 8 rows of one matrix per block. (R6-proven)
// ---------------------------------------------------------------------------
__global__ __launch_bounds__(256) void prep_uv(
    const float* __restrict__ span, const float* __restrict__ ant,
    const float* __restrict__ W1,   const float* __restrict__ b1,
    float* __restrict__ U, float* __restrict__ V)
{
    __shared__ float a_lds[8 * DDIM];    // 4 KB

    const int tid  = threadIdx.x;
    const int mat  = blockIdx.x & 1;     // 0 -> U (span), 1 -> V (ant)
    const int rblk = blockIdx.x >> 1;    // 0..127, 8 rows each
    const float* __restrict__ A = mat ? ant : span;
    float* __restrict__ outp    = mat ? V : U;

    ((float4*)a_lds)[tid] = ((const float4*)(A + rblk * 8 * DDIM))[tid];
    __syncthreads();

    const int c  = tid & 127;
    const int rg = tid >> 7;             // 0/1 -> rows rg*4..rg*4+3
    const float binit = mat ? 0.0f : b1[c];
    float acc0 = binit, acc1 = binit, acc2 = binit, acc3 = binit;

    const float* __restrict__ Wx = W1 + (mat ? DDIM * DDIM : 0);
    const float* __restrict__ Wc = W1 + 2 * DDIM * DDIM;
    const float sgn = mat ? -1.0f : 1.0f;

#pragma unroll 4
    for (int d0 = 0; d0 < DDIM; d0 += 4) {
        float w0 = Wx[(d0 + 0) * DDIM + c] + sgn * Wc[(d0 + 0) * DDIM + c];
        float w1 = Wx[(d0 + 1) * DDIM + c] + sgn * Wc[(d0 + 1) * DDIM + c];
        float w2 = Wx[(d0 + 2) * DDIM + c] + sgn * Wc[(d0 + 2) * DDIM + c];
        float w3 = Wx[(d0 + 3) * DDIM + c] + sgn * Wc[(d0 + 3) * DDIM + c];
        float4 a0 = *(const float4*)&a_lds[(rg * 4 + 0) * DDIM + d0];
        float4 a1 = *(const float4*)&a_lds[(rg * 4 + 1) * DDIM + d0];
        float4 a2 = *(const float4*)&a_lds[(rg * 4 + 2) * DDIM + d0];
        float4 a3 = *(const float4*)&a_lds[(rg * 4 + 3) * DDIM + d0];
        acc0 += a0.x * w0 + a0.y * w1 + a0.z * w2 + a0.w * w3;
        acc1 += a1.x * w0 + a1.y * w1 + a1.z * w2 + a1.w * w3;
        acc2 += a2.x * w0 + a2.y * w1 + a2.z * w2 + a2.w * w3;
        acc3 += a3.x * w0 + a3.y * w1 + a3.z * w2 + a3.w * w3;
    }
    const int rbase = rblk * 8 + rg * 4;
    outp[(rbase + 0) * DDIM + c] = acc0;
    outp[(rbase + 1) * DDIM + c] = acc1;
    outp[(rbase + 2) * DDIM + c] = acc2;
    outp[(rbase + 3) * DDIM + c] = acc3;
}

// ---------------------------------------------------------------------------
// Kernel 2: out[i][j] = (i>j) ? b2 + sum_c relu(U[i][c]+V[j][c])*W2[c] : 0
// grid (32,32) of 32x32 tiles, 256 threads (4 waves/block -> 8+ waves/CU:
// the R11 lesson — 1-wave blocks expose LDS latency, 4-wave blocks hide it).
// 2x2 micro-tile, stride-16 mapping: i = ti + 16a, j = tj + 16b (a,b < 2).
//   U reads (per instr): 4 addrs, 16-lane broadcast, banks 0/4/8/12 -> conflict-free
//   V reads: 16 addrs, banks 4*tj mod 32 -> 2-way alias (free, m136)
// W2 from LDS same-address broadcast; NO scalar loads in loop (R10 lesson).
// LDS ~34 KB -> 4 blocks/CU. 528 compute blocks, correct exact-tile zero-fill.
// ---------------------------------------------------------------------------
__global__ __launch_bounds__(256) void pair_score(
    const float* __restrict__ U, const float* __restrict__ V,
    const float* __restrict__ W2, const float* __restrict__ b2,
    float* __restrict__ out)
{
    const int bj  = blockIdx.x;   // column tile
    const int bi  = blockIdx.y;   // row tile
    const int tid = threadIdx.x;

    if (bi < bj) {
        // strictly-upper tile: zero-fill EXACTLY this 32x32 tile (256 float4).
        const int r  = tid >> 3;          // 0..31
        const int c4 = tid & 7;           // 8 float4 per 32-col row
        *(float4*)&out[(bi * TS + r) * KDIM + bj * TS + c4 * 4] =
            make_float4(0.f, 0.f, 0.f, 0.f);
        return;
    }

    __shared__ float Ul[TS * LDP];            // 16.9 KB
    __shared__ float Vl[TS * LDP];            // 16.9 KB
    __shared__ float W2l[DDIM];               // 0.5 KB

    {   // stage tiles: 1024 float4 each, 4 per thread
        const float4* us = (const float4*)(U + bi * TS * DDIM);
        const float4* vs = (const float4*)(V + bj * TS * DDIM);
#pragma unroll
        for (int k = 0; k < 4; ++k) {
            int idx = tid + k * 256;          // 0..1023
            int r   = idx >> 5;               // 32 float4 per row
            int c4  = idx & 31;
            *(float4*)&Ul[r * LDP + c4 * 4] = us[idx];
            *(float4*)&Vl[r * LDP + c4 * 4] = vs[idx];
        }
        if (tid < 32) *(float4*)&W2l[tid * 4] = *(const float4*)&W2[tid * 4];
    }
    __syncthreads();

    const int ti = tid >> 4;                  // 0..15, i = ti + 16a (a<2)
    const int tj = tid & 15;                  // 0..15, j = tj + 16b (b<2)
    const f2 z2 = {0.f, 0.f};

    f2 acc[2][2][2];
#pragma unroll
    for (int a = 0; a < 2; ++a)
#pragma unroll
        for (int b = 0; b < 2; ++b) { acc[a][b][0] = z2; acc[a][b][1] = z2; }

#pragma unroll 4
    for (int d = 0; d < DDIM; d += 4) {
        f2 ul[2][2], vl[2][2], w[2];
        {
            float4 x = *(const float4*)&W2l[d];
            w[0] = f2{x.x, x.y}; w[1] = f2{x.z, x.w};
        }
#pragma unroll
        for (int a = 0; a < 2; ++a) {
            float4 x = *(const float4*)&Ul[(ti + 16 * a) * LDP + d];
            ul[a][0] = f2{x.x, x.y}; ul[a][1] = f2{x.z, x.w};
        }
#pragma unroll
        for (int b = 0; b < 2; ++b) {
            float4 x = *(const float4*)&Vl[(tj + 16 * b) * LDP + d];
            vl[b][0] = f2{x.x, x.y}; vl[b][1] = f2{x.z, x.w};
        }
#pragma unroll
        for (int a = 0; a < 2; ++a)
#pragma unroll
            for (int b = 0; b < 2; ++b) {
                f2 t0 = __builtin_elementwise_max(ul[a][0] + vl[b][0], z2);
                f2 t1 = __builtin_elementwise_max(ul[a][1] + vl[b][1], z2);
                acc[a][b][0] += t0 * w[0];
                acc[a][b][1] += t1 * w[1];
            }
    }

    const float b2v = b2[0];
#pragma unroll
    for (int a = 0; a < 2; ++a) {
        const int gi = bi * TS + ti + 16 * a;
#pragma unroll
        for (int b = 0; b < 2; ++b) {
            const int gj = bj * TS + tj + 16 * b;
            f2 s2 = acc[a][b][0] + acc[a][b][1];
            float s = s2.x + s2.y + b2v;
            out[gi * KDIM + gj] = (gi > gj) ? s : 0.f;
        }
    }
}

// ---------------------------------------------------------------------------
extern "C" void kernel_launch(void* const* d_in, const int* in_sizes, int n_in,
                              void* d_out, int out_size, void* d_ws, size_t ws_size,
                              hipStream_t stream)
{
    const float* span = (const float*)d_in[0];
    const float* ant  = (const float*)d_in[1];
    const float* W1   = (const float*)d_in[2];
    const float* b1   = (const float*)d_in[3];
    const float* W2   = (const float*)d_in[4];
    const float* b2   = (const float*)d_in[5];
    float* out = (float*)d_out;

    float* U = (float*)d_ws;                 // 1024*128 floats (512 KB)
    float* V = U + KDIM * DDIM;              // next 512 KB (1 MB ws total)

    prep_uv<<<dim3(256), 256, 0, stream>>>(span, ant, W1, b1, U, V);
    pair_score<<<dim3(32, 32), 256, 0, stream>>>(U, V, W2, b2, out);
}